// Round 5
// baseline (347.512 us; speedup 1.0000x reference)
//
#include <hip/hip_runtime.h>
#include <hip/hip_bf16.h>

// LSTM decoder: B=2048, L=64, H=128, O=64, T=512.  Output: FLOAT32 [B,T,O].
// Identities:
//   next input x == h  =>  t>=1: gates = h @ (W_ih+W_hh)^T + (b_ih+b_hh)
//   t==0 (x=0):            gates = h0 @ W_hh^T + (b_ih+b_hh)
// Precision: LDS h rows 2b=hi(h_b), 2b+1=lo(h_b); one MFMA pass vs Whi;
//   acc[even]+acc[odd] = (hi+lo)@Whi  (h full precision, W bf16-rounded once).
// Schedule per step (this round): gates MFMA first -> out-proj MFMA (prev step,
//   same af) -> cell VALU overlaps out MFMAs -> LDS write (conflict-free
//   swizzle) -> barrier -> deferred out stores -> af read.
// Swizzle: byte = (row*256 + col*2) ^ swz(row), swz(r)=((r&7)<<4)^((r&8)<<2)
//   -> h-write rows {j,4+j,8+j,12+j} land in disjoint bank octets.

#define H_DIM 128
#define L_DIM 64
#define O_DIM 64
#define ROWS 8
#define THREADS 512
#define LOG2E 1.44269504f

typedef __attribute__((ext_vector_type(4))) float f32x4;
typedef __attribute__((ext_vector_type(4))) float float4v;
typedef __attribute__((ext_vector_type(8))) __bf16 bf16x8;
typedef __attribute__((ext_vector_type(8))) unsigned short u16x8;

__device__ __forceinline__ unsigned swzf(int r) {
  return (unsigned)(((r & 7) << 4) ^ ((r & 8) << 2));
}
__device__ __forceinline__ float fast_exp2(float x) {
#if __has_builtin(__builtin_amdgcn_exp2f)
  return __builtin_amdgcn_exp2f(x);
#else
  return exp2f(x);
#endif
}
__device__ __forceinline__ float fast_rcp(float x) {
#if __has_builtin(__builtin_amdgcn_rcpf)
  return __builtin_amdgcn_rcpf(x);
#else
  return 1.0f / x;
#endif
}
__device__ __forceinline__ float sigm_y(float y) {   // y = log2e * x
  return fast_rcp(1.0f + fast_exp2(-y));
}
__device__ __forceinline__ float tanh_y(float y) {   // y = 2*log2e * x
  return 1.0f - 2.0f * fast_rcp(1.0f + fast_exp2(y));
}
__device__ __forceinline__ unsigned short f2bf(float f) {
  unsigned u; __builtin_memcpy(&u, &f, 4);
  u = (u + 0x7FFFu + ((u >> 16) & 1u)) >> 16;
  return (unsigned short)u;
}
__device__ __forceinline__ void split2(float v, unsigned short& hi, unsigned short& lo) {
  __bf16 hb = (__bf16)v;
  __bf16 lb = (__bf16)(v - (float)hb);
  hi = __builtin_bit_cast(unsigned short, hb);
  lo = __builtin_bit_cast(unsigned short, lb);
}

// Recurrent-W fragments (bf16, gate scale folded: i,f,o x log2e; g x 2log2e).
__device__ __forceinline__ void load_wfrags(const float* __restrict__ W_ih,
                                            const float* __restrict__ W_hh,
                                            bool add_ih, int ub, int k0,
                                            bf16x8 wf[4][4]) {
  const float gsc[4] = {LOG2E, LOG2E, 2.0f * LOG2E, LOG2E};
#pragma unroll
  for (int g = 0; g < 4; ++g) {
    const float* ph = W_hh + (size_t)(g * 128 + ub) * H_DIM + k0;
    const float* pi = W_ih + (size_t)(g * 128 + ub) * H_DIM + k0;
    const float s = gsc[g];
#pragma unroll
    for (int kk = 0; kk < 4; ++kk) {
      float4v x0 = *(const float4v*)(ph + kk * 32);
      float4v x1 = *(const float4v*)(ph + kk * 32 + 4);
      if (add_ih) {
        x0 += *(const float4v*)(pi + kk * 32);
        x1 += *(const float4v*)(pi + kk * 32 + 4);
      }
      u16x8 b;
#pragma unroll
      for (int e = 0; e < 4; ++e) {
        b[e] = f2bf(s * x0[e]);
        b[e + 4] = f2bf(s * x1[e]);
      }
      wf[g][kk] = __builtin_bit_cast(bf16x8, b);
    }
  }
}

__global__ __launch_bounds__(THREADS, 2) void lstm_decoder_kernel(
    const float* __restrict__ latent, const float* __restrict__ fc_w,
    const float* __restrict__ fc_b, const float* __restrict__ W_ih,
    const float* __restrict__ W_hh, const float* __restrict__ b_ih,
    const float* __restrict__ b_hh, const float* __restrict__ Wo,
    const float* __restrict__ bo, const int* __restrict__ seq_len_p,
    float* __restrict__ out) {
  const int tid = threadIdx.x;
  const int lane = tid & 63;
  const int w = tid >> 6;            // wave 0..7
  const int row0 = blockIdx.x * ROWS;
  const int T = seq_len_p[0];

  // Double-buffered h tile: [16 rows][128 units] bf16; row 2b=hi, 2b+1=lo.
  __shared__ __align__(16) unsigned short hbuf[2][16 * 128];

  // ---- h0 = latent @ fc_w^T + fc_b  -> buf 0 ----
  {
    const int u = tid & 127;
    const int rbase = tid >> 7;  // 0..3
#pragma unroll
    for (int pp = 0; pp < 2; ++pp) {
      const int bl = rbase + pp * 4;  // 0..7
      const float4v* lat4 = (const float4v*)(latent + (size_t)(row0 + bl) * L_DIM);
      const float4v* fw4  = (const float4v*)(fc_w + (size_t)u * L_DIM);
      float s = fc_b[u];
#pragma unroll
      for (int j = 0; j < L_DIM / 4; ++j) {
        float4v a = lat4[j], b = fw4[j];
        s += a[0] * b[0] + a[1] * b[1] + a[2] * b[2] + a[3] * b[3];
      }
      const int mh = 2 * bl, ml = 2 * bl + 1;
      unsigned short hh, ll;
      split2(s, hh, ll);
      *(unsigned short*)((char*)hbuf[0] + ((unsigned)(mh * 256 + u * 2) ^ swzf(mh))) = hh;
      *(unsigned short*)((char*)hbuf[0] + ((unsigned)(ml * 256 + u * 2) ^ swzf(ml))) = ll;
    }
  }

  // ---- per-lane constants ----
  const int ub = (w << 4) + (lane & 15);   // this lane's hidden unit
  const int k0 = (lane >> 4) << 3;
  const float gscb[4] = {LOG2E, LOG2E, 2.0f * LOG2E, LOG2E};
  float bias_g[4];
#pragma unroll
  for (int g = 0; g < 4; ++g)
    bias_g[g] = gscb[g] * (b_ih[g * 128 + ub] + b_hh[g * 128 + ub]);

  const int ocol = ((w & 3) << 4) + (lane & 15);
  const float bo_l = bo[ocol];

  // Wo fragments, single bf16 (A side carries hi+lo)
  bf16x8 wofrag[4];
#pragma unroll
  for (int kk = 0; kk < 4; ++kk) {
    const float* p = Wo + (size_t)ocol * H_DIM + k0 + kk * 32;
    float4v x0 = *(const float4v*)p;
    float4v x1 = *(const float4v*)(p + 4);
    u16x8 b;
#pragma unroll
    for (int e = 0; e < 4; ++e) { b[e] = f2bf(x0[e]); b[e + 4] = f2bf(x1[e]); }
    wofrag[kk] = __builtin_bit_cast(bf16x8, b);
  }

  // step-0 weights: W_hh only (x0 = 0)
  bf16x8 wf[4][4];
  load_wfrags(W_ih, W_hh, /*add_ih=*/false, ub, k0, wf);

  __syncthreads();  // h0 visible

  // ---- A-fragment read (row = lane&15, k = kk*32 + (lane>>4)*8 + e) ----
  bf16x8 af[4];
  const unsigned asw = swzf(lane & 15);
  const unsigned abase = (unsigned)((lane & 15) * 256 + ((lane >> 4) << 4));
#pragma unroll
  for (int kk = 0; kk < 4; ++kk)
    af[kk] = *(const bf16x8*)((const char*)hbuf[0] + ((abase + kk * 64) ^ asw));

  // write offsets: rows 4lg..4lg+3 = hiA, loA, hiB, loB at column ub
  const int lg = lane >> 4;
  unsigned woff[4];
#pragma unroll
  for (int r = 0; r < 4; ++r) {
    const int m = 4 * lg + r;
    woff[r] = (unsigned)((m * 256 + ub * 2) ^ swzf(m));
  }

  float cA = 0.0f, cB = 0.0f;  // cell state for batch rows 2*lg, 2*lg+1
  float* pa = out + (size_t)(row0 + 2 * lg) * T * O_DIM + ocol;
  float* pb = out + (size_t)(row0 + 2 * lg + 1) * T * O_DIM + ocol;

  // Iteration k (af = h_k at entry): gates_k -> h_{k+1}; out_{k-1} from af;
  // out stores deferred past the barrier (vmcnt drained by NEXT barrier).
  auto halfstep = [&](unsigned short* dst, bool first, bool reload) {
    // 1) gate MFMAs first — the cell's only dependency
    f32x4 acc[4];
#pragma unroll
    for (int g = 0; g < 4; ++g) {
      f32x4 a = {bias_g[g], 0.0f, bias_g[g], 0.0f};
#pragma unroll
      for (int kk = 0; kk < 4; ++kk)
        a = __builtin_amdgcn_mfma_f32_16x16x32_bf16(af[kk], wf[g][kk], a, 0, 0, 0);
      acc[g] = a;
    }

    // 2) out-proj MFMAs for step k-1 (same af); overlap with cell below
    f32x4 ao = {0.0f, 0.0f, 0.0f, 0.0f};
    if (w < 4) {
      f32x4 a = {bo_l, 0.0f, bo_l, 0.0f};
#pragma unroll
      for (int kk = 0; kk < 4; ++kk)
        a = __builtin_amdgcn_mfma_f32_16x16x32_bf16(af[kk], wofrag[kk], a, 0, 0, 0);
      ao = a;
    }

    // 3) element-wise cell (rows 2lg, 2lg+1)
    float hA, hB;
    {
      float yi = acc[0][0] + acc[0][1], yf = acc[1][0] + acc[1][1];
      float yg = acc[2][0] + acc[2][1], yo = acc[3][0] + acc[3][1];
      cA = sigm_y(yf) * cA + sigm_y(yi) * tanh_y(yg);
      hA = sigm_y(yo) * tanh_y(2.0f * LOG2E * cA);
      yi = acc[0][2] + acc[0][3]; yf = acc[1][2] + acc[1][3];
      yg = acc[2][2] + acc[2][3]; yo = acc[3][2] + acc[3][3];
      cB = sigm_y(yf) * cB + sigm_y(yi) * tanh_y(yg);
      hB = sigm_y(yo) * tanh_y(2.0f * LOG2E * cB);
    }

    // 4) write h_{k+1} (conflict-free swizzle)
    {
      unsigned short hh, ll;
      split2(hA, hh, ll);
      *(unsigned short*)((char*)dst + woff[0]) = hh;
      *(unsigned short*)((char*)dst + woff[1]) = ll;
      split2(hB, hh, ll);
      *(unsigned short*)((char*)dst + woff[2]) = hh;
      *(unsigned short*)((char*)dst + woff[3]) = ll;
    }

    if (reload)  // once, after step 0: switch to combined (W_ih+W_hh)
      load_wfrags(W_ih, W_hh, /*add_ih=*/true, ub, k0, wf);

    __syncthreads();  // h_{k+1} visible

    // 5) deferred out_{k-1} stores (post-barrier; no vmcnt drain this phase)
    if (w < 4 && !first) {
      *pa = ao[0] + ao[1];
      *pb = ao[2] + ao[3];
      pa += O_DIM;
      pb += O_DIM;
    }

    // 6) read h_{k+1} fragments
#pragma unroll
    for (int kk = 0; kk < 4; ++kk)
      af[kk] = *(const bf16x8*)((const char*)dst + ((abase + kk * 64) ^ asw));
  };

#pragma unroll 1
  for (int tt = 0; tt < (T >> 1); ++tt) {
    halfstep(hbuf[1], tt == 0, tt == 0);
    halfstep(hbuf[0], false, false);
  }
  if (T & 1) halfstep(hbuf[1], T == 1, T == 1);

  // final out_{T-1} from af = h_T
  if (w < 4 && T > 0) {
    f32x4 a = {bo_l, 0.0f, bo_l, 0.0f};
#pragma unroll
    for (int kk = 0; kk < 4; ++kk)
      a = __builtin_amdgcn_mfma_f32_16x16x32_bf16(af[kk], wofrag[kk], a, 0, 0, 0);
    *pa = a[0] + a[1];
    *pb = a[2] + a[3];
  }
}

extern "C" void kernel_launch(void* const* d_in, const int* in_sizes, int n_in,
                              void* d_out, int out_size, void* d_ws, size_t ws_size,
                              hipStream_t stream) {
  const float* latent = (const float*)d_in[0];
  const float* fc_w   = (const float*)d_in[1];
  const float* fc_b   = (const float*)d_in[2];
  const float* W_ih   = (const float*)d_in[3];
  const float* W_hh   = (const float*)d_in[4];
  const float* b_ih   = (const float*)d_in[5];
  const float* b_hh   = (const float*)d_in[6];
  const float* Wo     = (const float*)d_in[7];
  const float* bo     = (const float*)d_in[8];
  const int* seq_len  = (const int*)d_in[9];
  float* out = (float*)d_out;

  const int B = in_sizes[0] / L_DIM;  // 2048
  const int blocks = B / ROWS;        // 256 WGs -> 1 per CU

  hipLaunchKernelGGL(lstm_decoder_kernel, dim3(blocks), dim3(THREADS), 0, stream,
                     latent, fc_w, fc_b, W_ih, W_hh, b_ih, b_hh, Wo, bo, seq_len, out);
}

// Round 6
// 325.025 us; speedup vs baseline: 1.0692x; 1.0692x over previous
//
#include <hip/hip_runtime.h>
#include <hip/hip_bf16.h>

// LSTM decoder: B=2048, L=64, H=128, O=64, T=512.  Output: FLOAT32 [B,T,O].
// Identities:
//   next input x == h  =>  t>=1: gates = h @ (W_ih+W_hh)^T + (b_ih+b_hh)
//   t==0 (x=0):            gates = h0 @ W_hh^T + (b_ih+b_hh)
// Precision: LDS h rows 2b=hi(h_b), 2b+1=lo(h_b); one MFMA pass vs W(bf16);
//   acc[even]+acc[odd] = (hi+lo)@W  (h full precision, W bf16-rounded once).
// This round (r6): r4 skeleton + (a) shared-rcp cell: pair the two cells'
//   reciprocals and fuse sigma(i)*tanh(g) -> 15 trans ops/lane/step vs 20;
//   (b) s_setprio(1) around MFMA clusters to anti-phase the 2 waves/SIMD.

#define H_DIM 128
#define L_DIM 64
#define O_DIM 64
#define ROWS 8
#define THREADS 512
#define LOG2E 1.44269504f

typedef __attribute__((ext_vector_type(4))) float f32x4;
typedef __attribute__((ext_vector_type(4))) float float4v;
typedef __attribute__((ext_vector_type(8))) __bf16 bf16x8;
typedef __attribute__((ext_vector_type(8))) unsigned short u16x8;

__device__ __forceinline__ unsigned swzf(int r) {
  return (unsigned)(((r & 7) << 4) ^ ((r & 8) << 2));
}
__device__ __forceinline__ float fast_exp2(float x) {
#if __has_builtin(__builtin_amdgcn_exp2f)
  return __builtin_amdgcn_exp2f(x);
#else
  return exp2f(x);
#endif
}
__device__ __forceinline__ float fast_rcp(float x) {
#if __has_builtin(__builtin_amdgcn_rcpf)
  return __builtin_amdgcn_rcpf(x);
#else
  return 1.0f / x;
#endif
}
__device__ __forceinline__ unsigned short f2bf(float f) {
  unsigned u; __builtin_memcpy(&u, &f, 4);
  u = (u + 0x7FFFu + ((u >> 16) & 1u)) >> 16;
  return (unsigned short)u;
}
__device__ __forceinline__ void split2(float v, unsigned short& hi, unsigned short& lo) {
  __bf16 hb = (__bf16)v;
  __bf16 lb = (__bf16)(v - (float)hb);
  hi = __builtin_bit_cast(unsigned short, hb);
  lo = __builtin_bit_cast(unsigned short, lb);
}

// Recurrent-W fragments (bf16, gate scale folded: i,f,o x log2e; g x 2log2e).
__device__ __forceinline__ void load_wfrags(const float* __restrict__ W_ih,
                                            const float* __restrict__ W_hh,
                                            bool add_ih, int ub, int k0,
                                            bf16x8 wf[4][4]) {
  const float gsc[4] = {LOG2E, LOG2E, 2.0f * LOG2E, LOG2E};
#pragma unroll
  for (int g = 0; g < 4; ++g) {
    const float* ph = W_hh + (size_t)(g * 128 + ub) * H_DIM + k0;
    const float* pi = W_ih + (size_t)(g * 128 + ub) * H_DIM + k0;
    const float s = gsc[g];
#pragma unroll
    for (int kk = 0; kk < 4; ++kk) {
      float4v x0 = *(const float4v*)(ph + kk * 32);
      float4v x1 = *(const float4v*)(ph + kk * 32 + 4);
      if (add_ih) {
        x0 += *(const float4v*)(pi + kk * 32);
        x1 += *(const float4v*)(pi + kk * 32 + 4);
      }
      u16x8 b;
#pragma unroll
      for (int e = 0; e < 4; ++e) {
        b[e] = f2bf(s * x0[e]);
        b[e + 4] = f2bf(s * x1[e]);
      }
      wf[g][kk] = __builtin_bit_cast(bf16x8, b);
    }
  }
}

__global__ __launch_bounds__(THREADS, 2) void lstm_decoder_kernel(
    const float* __restrict__ latent, const float* __restrict__ fc_w,
    const float* __restrict__ fc_b, const float* __restrict__ W_ih,
    const float* __restrict__ W_hh, const float* __restrict__ b_ih,
    const float* __restrict__ b_hh, const float* __restrict__ Wo,
    const float* __restrict__ bo, const int* __restrict__ seq_len_p,
    float* __restrict__ out) {
  const int tid = threadIdx.x;
  const int lane = tid & 63;
  const int w = tid >> 6;            // wave 0..7
  const int row0 = blockIdx.x * ROWS;
  const int T = seq_len_p[0];

  // Double-buffered h tile: [16 rows][128 units] bf16; row 2b=hi, 2b+1=lo.
  // phys byte = (row*256 + col*2) ^ swzf(row).
  __shared__ __align__(16) unsigned short hbuf[2][16 * 128];

  // ---- h0 = latent @ fc_w^T + fc_b  -> buf 0 ----
  {
    const int u = tid & 127;
    const int rbase = tid >> 7;  // 0..3
#pragma unroll
    for (int pp = 0; pp < 2; ++pp) {
      const int bl = rbase + pp * 4;  // 0..7
      const float4v* lat4 = (const float4v*)(latent + (size_t)(row0 + bl) * L_DIM);
      const float4v* fw4  = (const float4v*)(fc_w + (size_t)u * L_DIM);
      float s = fc_b[u];
#pragma unroll
      for (int j = 0; j < L_DIM / 4; ++j) {
        float4v a = lat4[j], b = fw4[j];
        s += a[0] * b[0] + a[1] * b[1] + a[2] * b[2] + a[3] * b[3];
      }
      const int mh = 2 * bl, ml = 2 * bl + 1;
      unsigned short hh, ll;
      split2(s, hh, ll);
      *(unsigned short*)((char*)hbuf[0] + ((unsigned)(mh * 256 + u * 2) ^ swzf(mh))) = hh;
      *(unsigned short*)((char*)hbuf[0] + ((unsigned)(ml * 256 + u * 2) ^ swzf(ml))) = ll;
    }
  }

  // ---- per-lane constants ----
  const int ub = (w << 4) + (lane & 15);   // this lane's hidden unit
  const int k0 = (lane >> 4) << 3;
  const float gscb[4] = {LOG2E, LOG2E, 2.0f * LOG2E, LOG2E};
  float bias_g[4];
#pragma unroll
  for (int g = 0; g < 4; ++g)
    bias_g[g] = gscb[g] * (b_ih[g * 128 + ub] + b_hh[g * 128 + ub]);

  const int ocol = ((w & 3) << 4) + (lane & 15);
  const float bo_l = bo[ocol];

  // Wo fragments, single bf16 (A side carries hi+lo)
  bf16x8 wofrag[4];
#pragma unroll
  for (int kk = 0; kk < 4; ++kk) {
    const float* p = Wo + (size_t)ocol * H_DIM + k0 + kk * 32;
    float4v x0 = *(const float4v*)p;
    float4v x1 = *(const float4v*)(p + 4);
    u16x8 b;
#pragma unroll
    for (int e = 0; e < 4; ++e) { b[e] = f2bf(x0[e]); b[e + 4] = f2bf(x1[e]); }
    wofrag[kk] = __builtin_bit_cast(bf16x8, b);
  }

  // step-0 weights: W_hh only (x0 = 0)
  bf16x8 wf[4][4];
  load_wfrags(W_ih, W_hh, /*add_ih=*/false, ub, k0, wf);

  __syncthreads();  // h0 visible

  // ---- A-fragment read (row = lane&15, k = kk*32 + (lane>>4)*8 + e) ----
  bf16x8 af[4];
  const unsigned asw = swzf(lane & 15);
  const unsigned abase = (unsigned)((lane & 15) * 256 + ((lane >> 4) << 4));
#pragma unroll
  for (int kk = 0; kk < 4; ++kk)
    af[kk] = *(const bf16x8*)((const char*)hbuf[0] + ((abase + kk * 64) ^ asw));

  // write offsets: rows 4lg..4lg+3 = hiA, loA, hiB, loB at column ub
  const int lg = lane >> 4;
  unsigned woff[4];
#pragma unroll
  for (int r = 0; r < 4; ++r) {
    const int m = 4 * lg + r;
    woff[r] = (unsigned)((m * 256 + ub * 2) ^ swzf(m));
  }

  float cA = 0.0f, cB = 0.0f;  // cell state for batch rows 2*lg, 2*lg+1
  float* pa = out + (size_t)(row0 + 2 * lg) * T * O_DIM + ocol;
  float* pb = out + (size_t)(row0 + 2 * lg + 1) * T * O_DIM + ocol;

  auto halfstep = [&](unsigned short* dst, bool reload) {
    // 1) gate MFMAs (prio 1: keep the matrix pipe owned by the leading wave)
    f32x4 acc[4];
    __builtin_amdgcn_s_setprio(1);
#pragma unroll
    for (int g = 0; g < 4; ++g) {
      f32x4 a = {bias_g[g], 0.0f, bias_g[g], 0.0f};
#pragma unroll
      for (int kk = 0; kk < 4; ++kk)
        a = __builtin_amdgcn_mfma_f32_16x16x32_bf16(af[kk], wf[g][kk], a, 0, 0, 0);
      acc[g] = a;
    }
    __builtin_amdgcn_s_setprio(0);

    // 2) element-wise cell, shared-rcp form (15 trans/lane/step vs 20):
    //    sigma(f): paired rcp across cells A,B
    //    sigma(i)*tanh(g) = (Gg-1)/(Di*(Gg+1)): fused, paired rcp
    //    tanh(c): robust 1-2*rcp(1+exp2) form (handles c -> +-inf gracefully)
    //    h = sigma(o)*tanh(c): sigma(o) paired rcp
    float hA, hB;
    {
      float yiA = acc[0][0] + acc[0][1], yfA = acc[1][0] + acc[1][1];
      float ygA = acc[2][0] + acc[2][1], yoA = acc[3][0] + acc[3][1];
      float yiB = acc[0][2] + acc[0][3], yfB = acc[1][2] + acc[1][3];
      float ygB = acc[2][2] + acc[2][3], yoB = acc[3][2] + acc[3][3];

      float EiA = fast_exp2(-yiA), EfA = fast_exp2(-yfA);
      float GgA = fast_exp2(ygA),  EoA = fast_exp2(-yoA);
      float EiB = fast_exp2(-yiB), EfB = fast_exp2(-yfB);
      float GgB = fast_exp2(ygB),  EoB = fast_exp2(-yoB);

      // sigma(f) pair
      float DfA = 1.0f + EfA, DfB = 1.0f + EfB;
      float rf = fast_rcp(DfA * DfB);
      float sfA = rf * DfB, sfB = rf * DfA;

      // sigma(i)*tanh(g) pair (fused)
      float DiGA = (1.0f + EiA) * (1.0f + GgA);
      float DiGB = (1.0f + EiB) * (1.0f + GgB);
      float rg = fast_rcp(DiGA * DiGB);
      float sitA = (GgA - 1.0f) * (rg * DiGB);
      float sitB = (GgB - 1.0f) * (rg * DiGA);

      cA = sfA * cA + sitA;
      cB = sfB * cB + sitB;

      // tanh(c): robust form
      float tcA = 1.0f - 2.0f * fast_rcp(1.0f + fast_exp2(2.0f * LOG2E * cA));
      float tcB = 1.0f - 2.0f * fast_rcp(1.0f + fast_exp2(2.0f * LOG2E * cB));

      // sigma(o) pair
      float DoA = 1.0f + EoA, DoB = 1.0f + EoB;
      float ro = fast_rcp(DoA * DoB);
      hA = (ro * DoB) * tcA;
      hB = (ro * DoA) * tcB;
    }

    // 3) write h_{k+1} split into the other buffer
    {
      unsigned short hh, ll;
      split2(hA, hh, ll);
      *(unsigned short*)((char*)dst + woff[0]) = hh;
      *(unsigned short*)((char*)dst + woff[1]) = ll;
      split2(hB, hh, ll);
      *(unsigned short*)((char*)dst + woff[2]) = hh;
      *(unsigned short*)((char*)dst + woff[3]) = ll;
    }

    if (reload)  // once, after step 0: switch to combined (W_ih+W_hh)
      load_wfrags(W_ih, W_hh, /*add_ih=*/true, ub, k0, wf);

    __syncthreads();  // h_{k+1} visible

    // 4) read h_{k+1} fragments
#pragma unroll
    for (int kk = 0; kk < 4; ++kk)
      af[kk] = *(const bf16x8*)((const char*)dst + ((abase + kk * 64) ^ asw));

    // 5) out_t = h_{k+1} @ Wo^T + bo  (waves 0-3), immediate store
    if (w < 4) {
      f32x4 ao = {bo_l, 0.0f, bo_l, 0.0f};
      __builtin_amdgcn_s_setprio(1);
#pragma unroll
      for (int kk = 0; kk < 4; ++kk)
        ao = __builtin_amdgcn_mfma_f32_16x16x32_bf16(af[kk], wofrag[kk], ao, 0, 0, 0);
      __builtin_amdgcn_s_setprio(0);
      *pa = ao[0] + ao[1];
      *pb = ao[2] + ao[3];
    }
    pa += O_DIM;
    pb += O_DIM;
  };

#pragma unroll 1
  for (int tt = 0; tt < (T >> 1); ++tt) {
    halfstep(hbuf[1], tt == 0);
    halfstep(hbuf[0], false);
  }
  if (T & 1) halfstep(hbuf[1], T == 1);
}

extern "C" void kernel_launch(void* const* d_in, const int* in_sizes, int n_in,
                              void* d_out, int out_size, void* d_ws, size_t ws_size,
                              hipStream_t stream) {
  const float* latent = (const float*)d_in[0];
  const float* fc_w   = (const float*)d_in[1];
  const float* fc_b   = (const float*)d_in[2];
  const float* W_ih   = (const float*)d_in[3];
  const float* W_hh   = (const float*)d_in[4];
  const float* b_ih   = (const float*)d_in[5];
  const float* b_hh   = (const float*)d_in[6];
  const float* Wo     = (const float*)d_in[7];
  const float* bo     = (const float*)d_in[8];
  const int* seq_len  = (const int*)d_in[9];
  float* out = (float*)d_out;

  const int B = in_sizes[0] / L_DIM;  // 2048
  const int blocks = B / ROWS;        // 256 WGs -> 1 per CU

  hipLaunchKernelGGL(lstm_decoder_kernel, dim3(blocks), dim3(THREADS), 0, stream,
                     latent, fc_w, fc_b, W_ih, W_hh, b_ih, b_hh, Wo, bo, seq_len, out);
}